// Round 6
// baseline (1092.537 us; speedup 1.0000x reference)
//
#include <hip/hip_runtime.h>

// GCN-EEGNet forward, MI355X. Dtype-adaptive (fp32/bf16 inputs detected in
// K0 via adjacency sentinel). Weights fp32 in ws, read with WAVE-UNIFORM
// indices -> SGPR operands. Big intermediates bf16 in ws (bufA/bufB).
// Round-6: k2 (sparse graph einsum) FUSED into k3 (gconv): per thread,
// graph-combine deg(c) neighbor rows into the fp32 conv window ev[12]
// (CSR col/vals are wave-uniform -> SGPR), then 8x8x8 conv from registers.
// Saves 262 MB HBM round-trip + ~2500 VALU ops/thread per layer vs split.
// Pipeline: K0 setup -> K1 conv1+bn -> 3x K23(graph+gconv+bn+elu, ping-pong)
// -> K4 dw+bn+elu+pool4 -> K5 sep(dw+pw)+bn+elu -> K6 pool8+fc.

#define B_   32
#define C_   64
#define T_   4000
#define F1_  8
#define TP_  1000
#define W2_  1001
#define MAXDEG 16

static __device__ __forceinline__ float bf2f(unsigned short h) {
  union { unsigned int u; float f; } v; v.u = ((unsigned int)h) << 16; return v.f;
}
static __device__ __forceinline__ float lo_f(unsigned int u) {
  union { unsigned int u; float f; } v; v.u = u << 16; return v.f;
}
static __device__ __forceinline__ float hi_f(unsigned int u) {
  union { unsigned int u; float f; } v; v.u = u & 0xFFFF0000u; return v.f;
}
static __device__ __forceinline__ unsigned short f2bf(float f) {
  union { float f; unsigned int u; } v; v.f = f;
  unsigned int r = v.u + 0x7FFFu + ((v.u >> 16) & 1u);
  return (unsigned short)(r >> 16);
}
static __device__ __forceinline__ float eluf(float z) {
  return z > 0.0f ? z : expm1f(z);
}
static __device__ __forceinline__ float ldin(const void* p, int i, int isf32) {
  return isf32 ? ((const float*)p)[i] : bf2f(((const unsigned short*)p)[i]);
}

// ---------------- K0: dtype detect + canonicalize + CSR + bn fold ----------
__global__ __launch_bounds__(256) void k0_setup(
    const void* __restrict__ adj, const void* __restrict__ imp,
    const void* __restrict__ dww, const void* __restrict__ w1,
    const void* __restrict__ bnF, const void* __restrict__ gw,
    const void* __restrict__ bnsp, const void* __restrict__ sdw,
    const void* __restrict__ pw, const void* __restrict__ bnsep,
    const void* __restrict__ fcw, const void* __restrict__ fcb,
    int* __restrict__ flag, int* __restrict__ deg, int* __restrict__ col,
    float* __restrict__ avals, float* __restrict__ w1c,
    float* __restrict__ gwc, float* __restrict__ dwn,
    float* __restrict__ sdwc, float* __restrict__ pwc,
    float* __restrict__ fcwc, float* __restrict__ fcbc,
    float* __restrict__ bnFs, float* __restrict__ bnsps,
    float* __restrict__ bnseps)
{
  __shared__ float dwr[1024];
  __shared__ float dsc[16];
  int tid = threadIdx.x;
  int isf32 = (((const float*)adj)[0] == 1.0f) ? 1 : 0;
  if (tid == 0) *flag = isf32;

  for (int i = tid; i < 512;  i += 256) w1c[i]  = ldin(w1, i, isf32);
  for (int i = tid; i < 1536; i += 256) gwc[i]  = ldin(gw, i, isf32);
  for (int i = tid; i < 256;  i += 256) sdwc[i] = ldin(sdw, i, isf32);
  for (int i = tid; i < 256;  i += 256) pwc[i]  = ldin(pw, i, isf32);
  for (int i = tid; i < 8000; i += 256) fcwc[i] = ldin(fcw, i, isf32);
  if (tid < 4) fcbc[tid] = ldin(fcb, tid, isf32);
  for (int i = tid; i < 1024; i += 256) dwr[i] = ldin(dww, i, isf32);

  if (tid < 64) {            // CSR of adjacency (data-driven)
    int c = tid, n = 0;
    for (int d = 0; d < 64; ++d) {
      if (ldin(adj, c*64 + d, isf32) != 0.0f) {
        if (n < MAXDEG) col[c*MAXDEG + n] = d;
        ++n;
      }
    }
    deg[c] = n < MAXDEG ? n : MAXDEG;
  }
  __syncthreads();
  if (tid < 16) {            // dw norm clamp scale
    float s2 = 0.0f;
    for (int c2 = 0; c2 < 64; ++c2) { float wv = dwr[tid*64 + c2]; s2 += wv*wv; }
    dsc[tid] = fminf(1.0f, 1.0f / fmaxf(sqrtf(s2), 1e-7f));
  }
  if (tid >= 64 && tid < 96) {   // bnF folded scale/shift: 4 stages x 8 ch
    int i = tid - 64, s = i >> 3, f = i & 7;
    float g = ldin(bnF, s*32 + f,      isf32);
    float b = ldin(bnF, s*32 + 8 + f,  isf32);
    float m = ldin(bnF, s*32 + 16 + f, isf32);
    float v = ldin(bnF, s*32 + 24 + f, isf32);
    float sc = g * rsqrtf(v + 1e-3f);
    bnFs[s*16 + f] = sc; bnFs[s*16 + 8 + f] = b - m*sc;
  }
  if (tid >= 96 && tid < 112) {  // bn_sp
    int ch = tid - 96;
    float g = ldin(bnsp, ch, isf32), b = ldin(bnsp, 16 + ch, isf32);
    float m = ldin(bnsp, 32 + ch, isf32), v = ldin(bnsp, 48 + ch, isf32);
    float sc = g * rsqrtf(v + 1e-3f);
    bnsps[ch] = sc; bnsps[16 + ch] = b - m*sc;
  }
  if (tid >= 112 && tid < 128) { // bn_sep
    int ch = tid - 112;
    float g = ldin(bnsep, ch, isf32), b = ldin(bnsep, 16 + ch, isf32);
    float m = ldin(bnsep, 32 + ch, isf32), v = ldin(bnsep, 48 + ch, isf32);
    float sc = g * rsqrtf(v + 1e-3f);
    bnseps[ch] = sc; bnseps[16 + ch] = b - m*sc;
  }
  for (int combo = tid; combo < 3*8*64; combo += 256) {
    int l = combo >> 9, f = (combo >> 6) & 7, c = combo & 63;
    int dg = deg[c];
    for (int e = 0; e < dg; ++e) {
      int d = col[c*MAXDEG + e];
      avals[((l*8 + f)*64 + c)*MAXDEG + e] =
          ldin(adj, c*64 + d, isf32) * ldin(imp, ((l*8 + f)*64 + c)*64 + d, isf32);
    }
  }
  __syncthreads();
  for (int i = tid; i < 1024; i += 256) dwn[i] = dwr[i] * dsc[i >> 6];
}

// ---------------- K1: conv1 (64-tap) + bn0. 4 t/thread, SGPR weights -------
// grid (4 t-tiles of 1024, B*C). Stage row from t=tb-35 so float4 reads align.
// Invariant entering chunk cc: A4 = xs[4tid+4+4cc ..], B4 = xs[4tid+8+4cc ..].
__global__ __launch_bounds__(256, 4) void k1_conv1_bn(
    const void* __restrict__ x,               // B,C,T raw dtype
    const float* __restrict__ w1c,            // 8x64 fp32 (uniform -> s_load)
    const float* __restrict__ bnFs,           // folded scale/shift
    const int* __restrict__ flag,
    unsigned short* __restrict__ outp)        // B,F1,C,T bf16
{
  __shared__ __align__(16) float xs[1096];    // t in [tb-35, tb+1059]
  int tid = threadIdx.x;
  int bc = blockIdx.y;                 // b*64+c
  int b = bc >> 6, c = bc & 63;
  int tb = blockIdx.x * 1024;
  int isf32 = *flag;
  int row = bc * T_;
  for (int s = tid; s < 1095; s += 256) {
    int t = tb - 35 + s;
    xs[s] = (t >= 0 && t < T_) ? ldin(x, row + t, isf32) : 0.0f;
  }
  __syncthreads();
  int t0 = tb + 4*tid;
  if (t0 >= T_) return;
  float acc[8][4];
  #pragma unroll
  for (int f = 0; f < 8; ++f)
    #pragma unroll
    for (int j = 0; j < 4; ++j) acc[f][j] = 0.0f;
  // chunk cc handles taps k=4cc..4cc+3; input t0+j+k-31 = element 4tid+4+4cc+(k-4cc)+j
  float4 A4 = *(const float4*)(xs + 4*tid + 4);
  float4 B4 = *(const float4*)(xs + 4*tid + 8);
  for (int cc = 0; cc < 16; ++cc) {
    float ev[7] = {A4.x, A4.y, A4.z, A4.w, B4.x, B4.y, B4.z};
    #pragma unroll
    for (int kk = 0; kk < 4; ++kk) {
      #pragma unroll
      for (int f = 0; f < 8; ++f) {
        float wv = w1c[f*64 + 4*cc + kk];    // uniform -> SGPR
        #pragma unroll
        for (int j = 0; j < 4; ++j) acc[f][j] = fmaf(wv, ev[kk + j], acc[f][j]);
      }
    }
    A4 = B4;
    if (cc < 15) B4 = *(const float4*)(xs + 4*tid + 12 + 4*cc);  // next B-half
  }
  #pragma unroll
  for (int f = 0; f < 8; ++f) {
    float sc = bnFs[f], sh = bnFs[8 + f];
    ushort4 v;
    v.x = f2bf(acc[f][0]*sc + sh);
    v.y = f2bf(acc[f][1]*sc + sh);
    v.z = f2bf(acc[f][2]*sc + sh);
    v.w = f2bf(acc[f][3]*sc + sh);
    *(ushort4*)(outp + ((b*8 + f)*64 + c)*T_ + t0) = v;
  }
}

// ---------------- K23: fused graph einsum + gconv + bn + elu ---------------
// grid (4 t-tiles of 1024, B*C), 4 t/thread, LDS-free. For each channel i:
// graph-combine deg(c) neighbor rows (CSR uniform -> SGPR) directly into the
// fp32 window ev[12] (t in [t0-4, t0+8)), then 8-tap conv into acc[8][4].
// Conv stage reads only registers. Edge lanes (t0==0 or t0+7>=T) guarded.
__global__ __launch_bounds__(256) void k23_fused(
    const unsigned short* __restrict__ in,    // B,F1,C,T bf16 (layer input)
    unsigned short* __restrict__ outp,        // B,F1,C,T bf16 (layer output)
    const int* __restrict__ deg, const int* __restrict__ col,
    const float* __restrict__ avals,          // 3,8,64,MAXDEG
    const float* __restrict__ gwc,            // 3x8x8x8 fp32 (uniform)
    const float* __restrict__ bnFs,
    int l)
{
  int tid = threadIdx.x;
  int bc = blockIdx.y;                 // b*64+c
  int b = bc >> 6, c = bc & 63;
  int t0 = blockIdx.x * 1024 + 4*tid;
  if (t0 >= T_) return;
  bool edge = (t0 == 0) || (t0 + 7 >= T_);   // window [t0-4, t0+7]
  int dgc = deg[c];                    // uniform -> SGPR
  float acc[8][4];
  #pragma unroll
  for (int o = 0; o < 8; ++o)
    #pragma unroll
    for (int j = 0; j < 4; ++j) acc[o][j] = 0.0f;
  const float* gl = gwc + l*512;
  for (int i = 0; i < 8; ++i) {
    const float* avi = avals + ((l*8 + i)*64 + c) * MAXDEG;  // uniform
    float ev[12];                      // ev[s] ~ t = t0-4+s, fp32
    #pragma unroll
    for (int s = 0; s < 12; ++s) ev[s] = 0.0f;
    for (int e = 0; e < dgc; ++e) {
      int d = col[c*MAXDEG + e];       // uniform
      float wv = avi[e];               // uniform
      int row = ((b*8 + i)*64 + d) * T_;
      if (!edge) {
        const unsigned short* rp = in + row + t0 - 4;
        uint2 u0 = *(const uint2*)(rp);
        uint2 u1 = *(const uint2*)(rp + 4);
        uint2 u2 = *(const uint2*)(rp + 8);
        ev[0] = fmaf(wv, lo_f(u0.x), ev[0]); ev[1] = fmaf(wv, hi_f(u0.x), ev[1]);
        ev[2] = fmaf(wv, lo_f(u0.y), ev[2]); ev[3] = fmaf(wv, hi_f(u0.y), ev[3]);
        ev[4] = fmaf(wv, lo_f(u1.x), ev[4]); ev[5] = fmaf(wv, hi_f(u1.x), ev[5]);
        ev[6] = fmaf(wv, lo_f(u1.y), ev[6]); ev[7] = fmaf(wv, hi_f(u1.y), ev[7]);
        ev[8] = fmaf(wv, lo_f(u2.x), ev[8]); ev[9] = fmaf(wv, hi_f(u2.x), ev[9]);
        ev[10]= fmaf(wv, lo_f(u2.y), ev[10]);ev[11]= fmaf(wv, hi_f(u2.y), ev[11]);
      } else {
        #pragma unroll
        for (int s = 0; s < 12; ++s) {
          int t = t0 - 4 + s;
          if (t >= 0 && t < T_) ev[s] = fmaf(wv, bf2f(in[row + t]), ev[s]);
        }
      }
    }
    #pragma unroll
    for (int k = 0; k < 8; ++k) {
      #pragma unroll
      for (int o = 0; o < 8; ++o) {
        float wv = gl[(o*8 + i)*8 + k];  // uniform -> SGPR
        #pragma unroll
        for (int j = 0; j < 4; ++j)
          acc[o][j] = fmaf(wv, ev[j + k + 1], acc[o][j]);  // in t = t0+j+k-3
      }
    }
  }
  #pragma unroll
  for (int o = 0; o < 8; ++o) {
    float sc = bnFs[(l+1)*16 + o], sh = bnFs[(l+1)*16 + 8 + o];
    ushort4 v;
    v.x = f2bf(eluf(acc[o][0]*sc + sh));
    v.y = f2bf(eluf(acc[o][1]*sc + sh));
    v.z = f2bf(eluf(acc[o][2]*sc + sh));
    v.w = f2bf(eluf(acc[o][3]*sc + sh));
    *(ushort4*)(outp + ((b*8 + o)*64 + c)*T_ + t0) = v;
  }
}

// ---------------- K4: depthwise-over-C + bn + elu + avgpool4. LDS-free -----
// grid (4 t-tiles of 1024, B*F1). 4 t/thread == one pool window exactly.
__global__ __launch_bounds__(256) void k4_dw(
    const unsigned short* __restrict__ in,    // B,F1,C,T bf16
    const float* __restrict__ dwn,            // 16x64 (uniform)
    const float* __restrict__ bnsps,
    float* __restrict__ p1)                   // B,16,1000 fp32
{
  int tid = threadIdx.x;
  int bg = blockIdx.y;                 // b*8+g
  int b = bg >> 3, g = bg & 7;
  int t0 = blockIdx.x * 1024 + 4*tid;
  if (t0 >= T_) return;
  int base = bg * (64 * T_);
  float a0[4] = {0,0,0,0}, a1[4] = {0,0,0,0};
  for (int cc = 0; cc < 64; ++cc) {
    float w0 = dwn[(2*g)*64 + cc];     // uniform
    float w1 = dwn[(2*g+1)*64 + cc];   // uniform
    uint2 v = *(const uint2*)(in + base + cc*T_ + t0);
    float h0 = lo_f(v.x), h1 = hi_f(v.x), h2 = lo_f(v.y), h3 = hi_f(v.y);
    a0[0] = fmaf(w0, h0, a0[0]); a0[1] = fmaf(w0, h1, a0[1]);
    a0[2] = fmaf(w0, h2, a0[2]); a0[3] = fmaf(w0, h3, a0[3]);
    a1[0] = fmaf(w1, h0, a1[0]); a1[1] = fmaf(w1, h1, a1[1]);
    a1[2] = fmaf(w1, h2, a1[2]); a1[3] = fmaf(w1, h3, a1[3]);
  }
  float sc0 = bnsps[2*g],     sh0 = bnsps[16 + 2*g];
  float sc1 = bnsps[2*g + 1], sh1 = bnsps[16 + 2*g + 1];
  float s0 = eluf(a0[0]*sc0 + sh0) + eluf(a0[1]*sc0 + sh0)
           + eluf(a0[2]*sc0 + sh0) + eluf(a0[3]*sc0 + sh0);
  float s1 = eluf(a1[0]*sc1 + sh1) + eluf(a1[1]*sc1 + sh1)
           + eluf(a1[2]*sc1 + sh1) + eluf(a1[3]*sc1 + sh1);
  int oi = t0 >> 2;
  p1[(b*16 + 2*g)*TP_ + oi]     = 0.25f * s0;
  p1[(b*16 + 2*g + 1)*TP_ + oi] = 0.25f * s1;
}

// ---------------- K5: sep depthwise(16) + pointwise(16x16) + bn + elu ------
// grid (4 w-tiles of 256, B).
__global__ __launch_bounds__(256) void k5_sep(
    const float* __restrict__ p1,             // B,16,1000
    const float* __restrict__ sdwc,           // 16x16 (uniform)
    const float* __restrict__ pwc,            // 16x16 (uniform)
    const float* __restrict__ bnseps,
    float* __restrict__ p2)                   // B,16,1001
{
  __shared__ float ps[16*272];
  int tid = threadIdx.x;
  int wq = blockIdx.x, b = blockIdx.y;
  int wb = wq * 256;
  for (int ch = 0; ch < 16; ++ch) {
    for (int s = tid; s < 272; s += 256) {
      int t = wb - 8 + s;
      ps[ch*272 + s] = (t >= 0 && t < TP_) ? p1[(b*16 + ch)*TP_ + t] : 0.0f;
    }
  }
  __syncthreads();
  int w0 = wb + tid;
  if (w0 >= W2_) return;
  float dws[16];
  for (int ch = 0; ch < 16; ++ch) {
    float a = 0.0f;
    #pragma unroll
    for (int k = 0; k < 16; ++k)
      a = fmaf(sdwc[ch*16 + k], ps[ch*272 + tid + k], a);
    dws[ch] = a;
  }
  for (int f = 0; f < 16; ++f) {
    float a = 0.0f;
    #pragma unroll
    for (int ch = 0; ch < 16; ++ch) a = fmaf(pwc[f*16 + ch], dws[ch], a);
    float sc = bnseps[f], sh = bnseps[16 + f];
    p2[(b*16 + f)*W2_ + w0] = eluf(a*sc + sh);
  }
}

// ---------------- K6: avgpool8 (first 1000) + fc ---------------------------
__global__ __launch_bounds__(256) void k6_fc(
    const float* __restrict__ p2,             // B,16,1001
    const float* __restrict__ fcwc,           // 4x2000
    const float* __restrict__ fcbc,           // 4
    const int* __restrict__ flag,
    void* __restrict__ outp)                  // B,4
{
  __shared__ float red[4*256];
  int tid = threadIdx.x;
  int b = blockIdx.x;
  float part[4] = {0.0f, 0.0f, 0.0f, 0.0f};
  for (int idx = tid; idx < 2000; idx += 256) {
    int f = idx / 125, q = idx - f*125;
    const float* src = p2 + (b*16 + f)*W2_ + q*8;
    float s = src[0]+src[1]+src[2]+src[3]+src[4]+src[5]+src[6]+src[7];
    float mval = 0.125f * s;
    #pragma unroll
    for (int n = 0; n < 4; ++n) part[n] = fmaf(fcwc[n*2000 + idx], mval, part[n]);
  }
  #pragma unroll
  for (int n = 0; n < 4; ++n) red[n*256 + tid] = part[n];
  __syncthreads();
  for (int s = 128; s > 0; s >>= 1) {
    if (tid < s) {
      #pragma unroll
      for (int n = 0; n < 4; ++n) red[n*256 + tid] += red[n*256 + tid + s];
    }
    __syncthreads();
  }
  if (tid < 4) {
    float val = red[tid*256] + fcbc[tid];
    if (*flag) ((float*)outp)[b*4 + tid] = val;
    else       ((unsigned short*)outp)[b*4 + tid] = f2bf(val);
  }
}

// ---------------------------------------------------------------------------
extern "C" void kernel_launch(void* const* d_in, const int* in_sizes, int n_in,
                              void* d_out, int out_size, void* d_ws, size_t ws_size,
                              hipStream_t stream) {
  const void* x     = d_in[0];
  const void* adj   = d_in[1];
  const void* w1    = d_in[2];
  const void* bnF   = d_in[3];
  const void* imp   = d_in[4];
  const void* gw    = d_in[5];
  const void* dww   = d_in[6];
  const void* bnsp  = d_in[7];
  const void* sdw   = d_in[8];
  const void* pw    = d_in[9];
  const void* bnsep = d_in[10];
  const void* fcw   = d_in[11];
  const void* fcb   = d_in[12];

  char* w = (char*)d_ws;
  const size_t OFF = 262144000;  // after two 131,072,000-byte bf16 buffers
  unsigned short* bufA = (unsigned short*)(w);
  unsigned short* bufB = (unsigned short*)(w + 131072000);
  int*   flag   = (int*)  (w + OFF + 0);
  int*   deg    = (int*)  (w + OFF + 256);
  int*   col    = (int*)  (w + OFF + 512);
  float* avals  = (float*)(w + OFF + 4608);
  float* w1c    = (float*)(w + OFF + 102912);
  float* gwc    = (float*)(w + OFF + 104960);
  float* dwn    = (float*)(w + OFF + 111104);
  float* sdwc   = (float*)(w + OFF + 115200);
  float* pwc    = (float*)(w + OFF + 116224);
  float* fcwc   = (float*)(w + OFF + 117248);
  float* fcbc   = (float*)(w + OFF + 149248);
  float* bnFs   = (float*)(w + OFF + 149504);
  float* bnsps  = (float*)(w + OFF + 149760);
  float* bnseps = (float*)(w + OFF + 150016);
  float* p1     = (float*)(w + OFF + 150272);
  float* p2     = (float*)(w + OFF + 2198272);

  k0_setup<<<1, 256, 0, stream>>>(adj, imp, dww, w1, bnF, gw, bnsp, sdw, pw,
                                  bnsep, fcw, fcb, flag, deg, col, avals,
                                  w1c, gwc, dwn, sdwc, pwc, fcwc, fcbc,
                                  bnFs, bnsps, bnseps);
  k1_conv1_bn<<<dim3(4, B_*C_), 256, 0, stream>>>(x, w1c, bnFs, flag, bufA);
  // ping-pong: A->B, B->A, A->B (k23 reads neighbor rows, must not alias out)
  k23_fused<<<dim3(4, B_*C_), 256, 0, stream>>>(bufA, bufB, deg, col, avals,
                                                gwc, bnFs, 0);
  k23_fused<<<dim3(4, B_*C_), 256, 0, stream>>>(bufB, bufA, deg, col, avals,
                                                gwc, bnFs, 1);
  k23_fused<<<dim3(4, B_*C_), 256, 0, stream>>>(bufA, bufB, deg, col, avals,
                                                gwc, bnFs, 2);
  k4_dw<<<dim3(4, B_*F1_), 256, 0, stream>>>(bufB, dwn, bnsps, p1);
  k5_sep<<<dim3(4, B_), 256, 0, stream>>>(p1, sdwc, pwc, bnseps, p2);
  k6_fc<<<32, 256, 0, stream>>>(p2, fcwc, fcbc, flag, d_out);
}